// Round 2
// baseline (489.153 us; speedup 1.0000x reference)
//
#include <hip/hip_runtime.h>
#include <hip/hip_bf16.h>
#include <math.h>

#define HD   512
#define D2   1024
#define SEQ  4096
#define BAT  16
#define BM   128     // s-rows per block
#define BK   32      // k per step
#define NKT  32      // 1024 / BK

typedef _Float16 half8 __attribute__((ext_vector_type(8)));
typedef float    f32x4 __attribute__((ext_vector_type(4)));
typedef __attribute__((address_space(3))) void lds_void_t;
typedef __attribute__((address_space(1))) void glb_void_t;

// ---------- kernel 0: W bottom-half -> f16, shuffled tile-major ----------
// WtS chunk layout: [kt 0..31][nh 0..1][c 0..1023] of 16B chunks,
// c = nbl*64 + kc*16 + nlo ; n = nh*256 + nbl*16 + nlo ; k = kt*32 + kc*8 + j.
// Per kt this is a LINEAR 32 KB block -> B staging is a pure linear
// global->LDS copy; frag reads phase-contiguous (uniform banks).
__global__ void wconv_kernel(const float* __restrict__ W, _Float16* __restrict__ WtS) {
  __shared__ float tile[32][17];
  const int kt  = blockIdx.x;        // 0..31
  const int nbg = blockIdx.y;        // 0..31
  const int nh  = nbg >> 4, nbl = nbg & 15;
  const int t   = threadIdx.x;       // 256
  {
    const int n16 = t & 15, kk = t >> 4;   // kk 0..15
    #pragma unroll
    for (int i = 0; i < 2; ++i) {
      const int k = kk + i * 16;
      tile[k][n16] = W[(size_t)(D2 + kt * 32 + k) * HD + nh * 256 + nbl * 16 + n16];
    }
  }
  __syncthreads();
  if (t < 64) {
    const int kc = t >> 4, nlo = t & 15;
    half8 h;
    #pragma unroll
    for (int j = 0; j < 8; ++j) h[j] = (_Float16)tile[kc * 8 + j][nlo];
    *(half8*)(WtS + ((size_t)(kt * 2 + nh) * 1024 + nbl * 64 + kc * 16 + nlo) * 8) = h;
  }
}

// ---------- kernel 1: h_proj[b,h] = hidden[b,:] . W_top[:,h] (atomic) ----------
__global__ void hproj_kernel(const float* __restrict__ hidden,
                             const float* __restrict__ W,
                             float* __restrict__ hproj) {
  const int b  = blockIdx.x >> 3;
  const int kc = blockIdx.x & 7;
  const int h  = threadIdx.x;
  float a0 = 0.f, a1 = 0.f;
  #pragma unroll 4
  for (int i = 0; i < 128; ++i) {
    const int d = kc * 128 + i;
    const float hd = hidden[b * D2 + d];
    a0 += hd * W[(size_t)d * HD + h];
    a1 += hd * W[(size_t)d * HD + h + 256];
  }
  atomicAdd(&hproj[b * HD + h], a0);
  atomicAdd(&hproj[b * HD + h + 256], a1);
}

// ---------- kernel 2: scores = w_v . tanh(enc.Wbot + h_proj + b_attn) ----------
// 128x512 tile, 512 thr (8 waves, wave tile 64x128), BK=32, triple-buffered LDS.
// m201-style 2-phase-per-K-step schedule (16 MFMA per phase, 8 per barrier):
//  phase A: ds_read B-frags (pre-barrier) | stageA issue | barrier | MFMA lo
//  phase B: stageB issue | vmcnt(6) | barrier | MFMA hi ∥ ds_read+cvt A(kt+1)
// setprio(1) around each MFMA cluster (T5). vmcnt never drains in main loop (T4).
__global__ __launch_bounds__(512, 2) void scores_kernel(
    const float* __restrict__ enc, const _Float16* __restrict__ WtS,
    const float* __restrict__ hproj, const float* __restrict__ b_attn,
    const float* __restrict__ w_v, float* __restrict__ scores)
{
  __shared__ __align__(16) float    As[3][BM * BK];     // 16 KB x3, f32, xor-swizzled chunks
  __shared__ __align__(16) _Float16 Bs[3][2048 * 8];    // 32 KB x3, chunk-major

  const int s0  = blockIdx.x * BM;
  const int b   = blockIdx.y;
  const int tid = threadIdx.x, lane = tid & 63, w = tid >> 6;
  const int col16 = lane & 15, q = lane >> 4;
  const int wm = w >> 2, wn = w & 3;   // wave tile: rows [wm*64,+64), cols [wn*128,+128)

  const float* encB = enc + ((size_t)b * SEQ + s0) * D2;

  f32x4 acc[4][8];
  const f32x4 z = {0.f, 0.f, 0.f, 0.f};
  #pragma unroll
  for (int mi = 0; mi < 4; ++mi)
    #pragma unroll
    for (int ni = 0; ni < 8; ++ni) acc[mi][ni] = z;

  auto stageA = [&](int kt, int buf) {
    // LDS slot s <- enc[row = s>>3][kt*32 + ((s&7)^(row&7))*4 ..+4)  (16B each)
    const float* ek = encB + kt * BK;
    #pragma unroll
    for (int i = 0; i < 2; ++i) {
      const int s = i * 512 + tid;
      const int row = s >> 3;
      const int g = (s & 7) ^ (row & 7);
      __builtin_amdgcn_global_load_lds((glb_void_t*)(ek + (size_t)row * D2 + g * 4),
          (lds_void_t*)((char*)&As[buf][0] + s * 16), 16, 0, 0);
    }
  };
  auto stageB = [&](int kt, int buf) {
    const _Float16* wk = WtS + (size_t)kt * 16384;
    #pragma unroll
    for (int i = 0; i < 4; ++i) {
      const int c = i * 512 + tid;
      __builtin_amdgcn_global_load_lds((glb_void_t*)(wk + c * 8),
          (lds_void_t*)((char*)&Bs[buf][0] + c * 16), 16, 0, 0);
    }
  };
  auto readA = [&](int buf, half8* af) {
    const float* pA = &As[buf][0];
    #pragma unroll
    for (int mi = 0; mi < 4; ++mi) {
      const int row = wm * 64 + mi * 16 + col16;
      const int rb = row * 8, rx = row & 7;
      const f32x4 lo = *(const f32x4*)&pA[(rb + ((2 * q)     ^ rx)) * 4];
      const f32x4 hi = *(const f32x4*)&pA[(rb + ((2 * q + 1) ^ rx)) * 4];
      half8 h;
      h[0] = (_Float16)lo[0]; h[1] = (_Float16)lo[1];
      h[2] = (_Float16)lo[2]; h[3] = (_Float16)lo[3];
      h[4] = (_Float16)hi[0]; h[5] = (_Float16)hi[1];
      h[6] = (_Float16)hi[2]; h[7] = (_Float16)hi[3];
      af[mi] = h;
    }
  };
  auto readB = [&](int buf, int half_, half8* bf) {   // half_=0: ni0..3, 1: ni4..7
    const _Float16* pB = &Bs[buf][0];
    #pragma unroll
    for (int ni = 0; ni < 4; ++ni)
      bf[ni] = *(const half8*)&pB[((wn * 8 + half_ * 4 + ni) * 64 + q * 16 + col16) * 8];
  };
  auto mfma16 = [&](const half8* af, const half8* bf, int nbase) {
    #pragma unroll
    for (int ni = 0; ni < 4; ++ni)
      #pragma unroll
      for (int mi = 0; mi < 4; ++mi)
        acc[mi][nbase + ni] =
            __builtin_amdgcn_mfma_f32_16x16x32_f16(af[mi], bf[ni], acc[mi][nbase + ni], 0, 0, 0);
  };

  half8 afA[4], afB[4];   // A frags, parity-alternating (compile-time selected)
  half8 bl[4], bh[4];     // B frags lo/hi of current kt

  // ---- prologue: two K-steps in flight, wait for the first only ----
  stageA(0, 0); stageB(0, 0);
  stageA(1, 1); stageB(1, 1);
  asm volatile("s_waitcnt vmcnt(6)" ::: "memory");
  __builtin_amdgcn_s_barrier();
  readA(0, afA);                      // af(0)

  // ---- main loop: kt = 0..29, 6-unrolled so parity & buf are constants ----
  for (int jo = 0; jo < 5; ++jo) {
    #pragma unroll
    for (int u = 0; u < 6; ++u) {
      const int kt = jo * 6 + u;
      const int bc = u % 3;                         // buf(kt)
      const int bn = (u + 1) % 3;                   // buf(kt+1)
      const int bs = (u + 2) % 3;                   // buf(kt+2)
      half8* afC = (u & 1) ? afB : afA;             // af(kt)
      half8* afN = (u & 1) ? afA : afB;             // af(kt+1)
      // phase A
      readB(bc, 0, bl);
      readB(bc, 1, bh);
      stageA(kt + 2, bs);
      __builtin_amdgcn_s_barrier();
      __builtin_amdgcn_s_setprio(1);
      mfma16(afC, bl, 0);
      __builtin_amdgcn_s_setprio(0);
      __builtin_amdgcn_s_barrier();
      // phase B
      stageB(kt + 2, bs);
      asm volatile("s_waitcnt vmcnt(6)" ::: "memory");   // stage(kt+1) landed
      __builtin_amdgcn_s_barrier();
      __builtin_amdgcn_s_setprio(1);
      mfma16(afC, bh, 4);
      readA(bn, afN);                  // A(kt+1): reads+cvt overlap the MFMAs
      __builtin_amdgcn_s_setprio(0);
      __builtin_amdgcn_s_barrier();
    }
  }

  // ---- tail: kt = 30 (buf 0), kt = 31 (buf 1); af(30) is in afA ----
  readB(0, 0, bl);
  readB(0, 1, bh);
  __builtin_amdgcn_s_barrier();
  __builtin_amdgcn_s_setprio(1);
  mfma16(afA, bl, 0);
  __builtin_amdgcn_s_setprio(0);
  __builtin_amdgcn_s_barrier();
  asm volatile("s_waitcnt vmcnt(0)" ::: "memory");       // stage(31) landed
  __builtin_amdgcn_s_barrier();
  __builtin_amdgcn_s_setprio(1);
  mfma16(afA, bh, 4);
  readA(1, afB);                        // af(31)
  __builtin_amdgcn_s_setprio(0);
  __builtin_amdgcn_s_barrier();
  readB(1, 0, bl);
  readB(1, 1, bh);
  __builtin_amdgcn_s_barrier();
  __builtin_amdgcn_s_setprio(1);
  mfma16(afB, bl, 0);
  mfma16(afB, bh, 4);
  __builtin_amdgcn_s_setprio(0);

  // ---- epilogue: tanh + dot(w_v), wave reduce, LDS cross-wave reduce ----
  float p[4][4];
  #pragma unroll
  for (int mi = 0; mi < 4; ++mi)
    #pragma unroll
    for (int r = 0; r < 4; ++r) p[mi][r] = 0.f;

  #pragma unroll
  for (int ni = 0; ni < 8; ++ni) {
    const int n = wn * 128 + ni * 16 + col16;
    const float hb = hproj[b * HD + n] + b_attn[n];
    const float wv = w_v[n];
    #pragma unroll
    for (int mi = 0; mi < 4; ++mi) {
      #pragma unroll
      for (int r = 0; r < 4; ++r) {
        float x = fminf(fmaxf(acc[mi][ni][r] + hb, -15.f), 15.f);
        float ex = __expf(2.f * x);
        p[mi][r] += wv * __fdividef(ex - 1.f, ex + 1.f);
      }
    }
  }
  #pragma unroll
  for (int off = 8; off >= 1; off >>= 1) {
    #pragma unroll
    for (int mi = 0; mi < 4; ++mi)
      #pragma unroll
      for (int r = 0; r < 4; ++r)
        p[mi][r] += __shfl_xor(p[mi][r], off, 64);
  }

  float* red = (float*)&As[0][0];      // 512 floats, reuses dead A buffer
  __syncthreads();
  if (col16 == 0) {
    #pragma unroll
    for (int mi = 0; mi < 4; ++mi)
      #pragma unroll
      for (int r = 0; r < 4; ++r)
        red[wn * 128 + wm * 64 + mi * 16 + q * 4 + r] = p[mi][r];
  }
  __syncthreads();
  if (tid < 128) {
    const float v = red[tid] + red[128 + tid] + red[256 + tid] + red[384 + tid];
    scores[b * SEQ + s0 + tid] = v;
  }
}

// ---------- kernel 3: softmax over S, in place ----------
__global__ void softmax_kernel(float* __restrict__ scores) {
  const int b = blockIdx.x;
  float* sc = scores + b * SEQ;
  __shared__ float red[16];
  const int tid = threadIdx.x;   // 256
  float loc[16];
  float mx = -1e30f;
  #pragma unroll
  for (int i = 0; i < 16; ++i) { loc[i] = sc[i * 256 + tid]; mx = fmaxf(mx, loc[i]); }
  #pragma unroll
  for (int off = 32; off >= 1; off >>= 1) mx = fmaxf(mx, __shfl_xor(mx, off, 64));
  if ((tid & 63) == 0) red[tid >> 6] = mx;
  __syncthreads();
  mx = fmaxf(fmaxf(red[0], red[1]), fmaxf(red[2], red[3]));
  float sum = 0.f;
  #pragma unroll
  for (int i = 0; i < 16; ++i) { loc[i] = __expf(loc[i] - mx); sum += loc[i]; }
  #pragma unroll
  for (int off = 32; off >= 1; off >>= 1) sum += __shfl_xor(sum, off, 64);
  if ((tid & 63) == 0) red[8 + (tid >> 6)] = sum;
  __syncthreads();
  sum = red[8] + red[9] + red[10] + red[11];
  const float inv = 1.0f / sum;
  #pragma unroll
  for (int i = 0; i < 16; ++i) sc[i * 256 + tid] = loc[i] * inv;
}

// ---------- kernel 4: context[b,d] = sum_s attn[b,s] * enc[b,s,d] ----------
__global__ __launch_bounds__(256) void context_kernel(const float* __restrict__ attn,
                                                      const float* __restrict__ enc,
                                                      float* __restrict__ out) {
  const int b  = blockIdx.y;
  const int s0 = blockIdx.x * 64;
  const int tid = threadIdx.x;   // 256 threads * float4 = 1024 d
  const float* encB = enc + ((size_t)b * SEQ + s0) * D2 + tid * 4;
  const float* at   = attn + b * SEQ + s0;
  f32x4 acc0 = {0.f, 0.f, 0.f, 0.f}, acc1 = {0.f, 0.f, 0.f, 0.f};
  #pragma unroll 8
  for (int i = 0; i < 64; i += 2) {
    acc0 += at[i]     * *(const f32x4*)(encB + (size_t)i * D2);
    acc1 += at[i + 1] * *(const f32x4*)(encB + (size_t)(i + 1) * D2);
  }
  f32x4 acc = acc0 + acc1;
  float* o = out + b * D2 + tid * 4;
  atomicAdd(o + 0, acc[0]);
  atomicAdd(o + 1, acc[1]);
  atomicAdd(o + 2, acc[2]);
  atomicAdd(o + 3, acc[3]);
}

extern "C" void kernel_launch(void* const* d_in, const int* in_sizes, int n_in,
                              void* d_out, int out_size, void* d_ws, size_t ws_size,
                              hipStream_t stream) {
  (void)in_sizes; (void)n_in; (void)ws_size;
  const float* hidden = (const float*)d_in[0];   // [16,1024]
  const float* enc    = (const float*)d_in[1];   // [16,4096,1024]
  const float* W      = (const float*)d_in[2];   // [2048,512]
  const float* b_attn = (const float*)d_in[3];   // [512]
  const float* w_v    = (const float*)d_in[4];   // [512]
  float* out = (float*)d_out;                    // [16,1024]

  char* ws = (char*)d_ws;
  _Float16* WtS = (_Float16*)ws;                     // 1 MB shuffled Wbot f16
  float* hproj  = (float*)(ws + (1 << 20));          // 32 KB
  float* scores = (float*)(ws + (1 << 20) + 32768);  // 256 KB (reused as attn)

  hipMemsetAsync(d_out, 0, (size_t)out_size * sizeof(float), stream);
  hipMemsetAsync(hproj, 0, BAT * HD * sizeof(float), stream);

  wconv_kernel  <<<dim3(32, 32),          256, 0, stream>>>(W, WtS);
  hproj_kernel  <<<dim3(128),             256, 0, stream>>>(hidden, W, hproj);
  scores_kernel <<<dim3(SEQ / BM, BAT),   512, 0, stream>>>(enc, WtS, hproj, b_attn, w_v, scores);
  softmax_kernel<<<dim3(BAT),             256, 0, stream>>>(scores);
  context_kernel<<<dim3(SEQ / 64, BAT),   256, 0, stream>>>(scores, enc, out);
}

// Round 4
// 473.489 us; speedup vs baseline: 1.0331x; 1.0331x over previous
//
#include <hip/hip_runtime.h>
#include <hip/hip_bf16.h>
#include <math.h>

#define HD   512
#define D2   1024
#define SEQ  4096
#define BAT  16
#define BM   128     // s-rows per block
#define BK   32      // k per step
#define NKT  32      // 1024 / BK

typedef _Float16 half8 __attribute__((ext_vector_type(8)));
typedef float    f32x4 __attribute__((ext_vector_type(4)));
typedef __attribute__((address_space(3))) void lds_void_t;
typedef __attribute__((address_space(1))) void glb_void_t;

// ---------- kernel 0: W bottom-half -> f16, shuffled tile-major ----------
// WtS chunk layout: [kt 0..31][nh 0..1][c 0..1023] of 16B chunks,
// c = nbl*64 + kc*16 + nlo ; n = nh*256 + nbl*16 + nlo ; k = kt*32 + kc*8 + j.
__global__ void wconv_kernel(const float* __restrict__ W, _Float16* __restrict__ WtS) {
  __shared__ float tile[32][17];
  const int kt  = blockIdx.x;        // 0..31
  const int nbg = blockIdx.y;        // 0..31
  const int nh  = nbg >> 4, nbl = nbg & 15;
  const int t   = threadIdx.x;       // 256
  {
    const int n16 = t & 15, kk = t >> 4;   // kk 0..15
    #pragma unroll
    for (int i = 0; i < 2; ++i) {
      const int k = kk + i * 16;
      tile[k][n16] = W[(size_t)(D2 + kt * 32 + k) * HD + nh * 256 + nbl * 16 + n16];
    }
  }
  __syncthreads();
  if (t < 64) {
    const int kc = t >> 4, nlo = t & 15;
    half8 h;
    #pragma unroll
    for (int j = 0; j < 8; ++j) h[j] = (_Float16)tile[kc * 8 + j][nlo];
    *(half8*)(WtS + ((size_t)(kt * 2 + nh) * 1024 + nbl * 64 + kc * 16 + nlo) * 8) = h;
  }
}

// ---------- kernel 1: h_proj[b,h] = hidden[b,:] . W_top[:,h] (atomic) ----------
__global__ void hproj_kernel(const float* __restrict__ hidden,
                             const float* __restrict__ W,
                             float* __restrict__ hproj) {
  const int b  = blockIdx.x >> 3;
  const int kc = blockIdx.x & 7;
  const int h  = threadIdx.x;
  float a0 = 0.f, a1 = 0.f;
  #pragma unroll 4
  for (int i = 0; i < 128; ++i) {
    const int d = kc * 128 + i;
    const float hd = hidden[b * D2 + d];
    a0 += hd * W[(size_t)d * HD + h];
    a1 += hd * W[(size_t)d * HD + h + 256];
  }
  atomicAdd(&hproj[b * HD + h], a0);
  atomicAdd(&hproj[b * HD + h + 256], a1);
}

// ---------- kernel 2: scores = w_v . tanh(enc.Wbot + h_proj + b_attn) ----------
// Same pipeline as R2, plus per-block cyclic K-rotation (kt0) to decorrelate
// the 128B column-window each block reads from enc at any instant ->
// spreads concurrent HBM requests across all channel-interleave groups.
__global__ __launch_bounds__(512, 2) void scores_kernel(
    const float* __restrict__ enc, const _Float16* __restrict__ WtS,
    const float* __restrict__ hproj, const float* __restrict__ b_attn,
    const float* __restrict__ w_v, float* __restrict__ scores)
{
  __shared__ __align__(16) float    As[3][BM * BK];     // 16 KB x3, f32, xor-swizzled chunks
  __shared__ __align__(16) _Float16 Bs[3][2048 * 8];    // 32 KB x3, chunk-major

  const int s0  = blockIdx.x * BM;
  const int b   = blockIdx.y;
  const int kt0 = (blockIdx.x + blockIdx.y) & 31;       // per-block K-phase offset
  const int tid = threadIdx.x, lane = tid & 63, w = tid >> 6;
  const int col16 = lane & 15, q = lane >> 4;
  const int wm = w >> 2, wn = w & 3;   // wave tile: rows [wm*64,+64), cols [wn*128,+128)

  const float* encB = enc + ((size_t)b * SEQ + s0) * D2;

  f32x4 acc[4][8];
  const f32x4 z = {0.f, 0.f, 0.f, 0.f};
  #pragma unroll
  for (int mi = 0; mi < 4; ++mi)
    #pragma unroll
    for (int ni = 0; ni < 8; ++ni) acc[mi][ni] = z;

  auto stageA = [&](int ktp, int buf) {
    // LDS slot s <- enc[row = s>>3][ktp*32 + ((s&7)^(row&7))*4 ..+4)  (16B each)
    const float* ek = encB + ktp * BK;
    #pragma unroll
    for (int i = 0; i < 2; ++i) {
      const int s = i * 512 + tid;
      const int row = s >> 3;
      const int g = (s & 7) ^ (row & 7);
      __builtin_amdgcn_global_load_lds((glb_void_t*)(ek + (size_t)row * D2 + g * 4),
          (lds_void_t*)((char*)&As[buf][0] + s * 16), 16, 0, 0);
    }
  };
  auto stageB = [&](int ktp, int buf) {
    const _Float16* wk = WtS + (size_t)ktp * 16384;
    #pragma unroll
    for (int i = 0; i < 4; ++i) {
      const int c = i * 512 + tid;
      __builtin_amdgcn_global_load_lds((glb_void_t*)(wk + c * 8),
          (lds_void_t*)((char*)&Bs[buf][0] + c * 16), 16, 0, 0);
    }
  };
  auto readA = [&](int buf, half8* af) {
    const float* pA = &As[buf][0];
    #pragma unroll
    for (int mi = 0; mi < 4; ++mi) {
      const int row = wm * 64 + mi * 16 + col16;
      const int rb = row * 8, rx = row & 7;
      const f32x4 lo = *(const f32x4*)&pA[(rb + ((2 * q)     ^ rx)) * 4];
      const f32x4 hi = *(const f32x4*)&pA[(rb + ((2 * q + 1) ^ rx)) * 4];
      half8 h;
      h[0] = (_Float16)lo[0]; h[1] = (_Float16)lo[1];
      h[2] = (_Float16)lo[2]; h[3] = (_Float16)lo[3];
      h[4] = (_Float16)hi[0]; h[5] = (_Float16)hi[1];
      h[6] = (_Float16)hi[2]; h[7] = (_Float16)hi[3];
      af[mi] = h;
    }
  };
  auto readB = [&](int buf, int half_, half8* bf) {   // half_=0: ni0..3, 1: ni4..7
    const _Float16* pB = &Bs[buf][0];
    #pragma unroll
    for (int ni = 0; ni < 4; ++ni)
      bf[ni] = *(const half8*)&pB[((wn * 8 + half_ * 4 + ni) * 64 + q * 16 + col16) * 8];
  };
  auto mfma16 = [&](const half8* af, const half8* bf, int nbase) {
    #pragma unroll
    for (int ni = 0; ni < 4; ++ni)
      #pragma unroll
      for (int mi = 0; mi < 4; ++mi)
        acc[mi][nbase + ni] =
            __builtin_amdgcn_mfma_f32_16x16x32_f16(af[mi], bf[ni], acc[mi][nbase + ni], 0, 0, 0);
  };

  half8 afA[4], afB[4];   // A frags, parity-alternating (compile-time selected)
  half8 bl[4], bh[4];     // B frags lo/hi of current kt

  // ---- prologue: two K-steps in flight, wait for the first only ----
  stageA(kt0, 0); stageB(kt0, 0);
  stageA((kt0 + 1) & 31, 1); stageB((kt0 + 1) & 31, 1);
  asm volatile("s_waitcnt vmcnt(6)" ::: "memory");
  __builtin_amdgcn_s_barrier();
  readA(0, afA);                      // af(0)

  // ---- main loop: kt = 0..29 logical, 6-unrolled so parity & buf are constants ----
  for (int jo = 0; jo < 5; ++jo) {
    #pragma unroll
    for (int u = 0; u < 6; ++u) {
      const int kt = jo * 6 + u;
      const int ktp2 = (kt + 2 + kt0) & 31;             // physical K-step to stage
      const int bc = u % 3;                             // buf(kt)
      const int bn = (u + 1) % 3;                       // buf(kt+1)
      const int bs = (u + 2) % 3;                       // buf(kt+2)
      half8* afC = (u & 1) ? afB : afA;                 // af(kt)
      half8* afN = (u & 1) ? afA : afB;                 // af(kt+1)
      // phase A
      readB(bc, 0, bl);
      readB(bc, 1, bh);
      stageA(ktp2, bs);
      __builtin_amdgcn_s_barrier();
      __builtin_amdgcn_s_setprio(1);
      mfma16(afC, bl, 0);
      __builtin_amdgcn_s_setprio(0);
      __builtin_amdgcn_s_barrier();
      // phase B
      stageB(ktp2, bs);
      asm volatile("s_waitcnt vmcnt(6)" ::: "memory");   // stage(kt+1) landed
      __builtin_amdgcn_s_barrier();
      __builtin_amdgcn_s_setprio(1);
      mfma16(afC, bh, 4);
      readA(bn, afN);                  // A(kt+1): reads+cvt overlap the MFMAs
      __builtin_amdgcn_s_setprio(0);
      __builtin_amdgcn_s_barrier();
    }
  }

  // ---- tail: logical kt = 30 (buf 0), kt = 31 (buf 1); af(30) is in afA ----
  readB(0, 0, bl);
  readB(0, 1, bh);
  __builtin_amdgcn_s_barrier();
  __builtin_amdgcn_s_setprio(1);
  mfma16(afA, bl, 0);
  __builtin_amdgcn_s_setprio(0);
  __builtin_amdgcn_s_barrier();
  asm volatile("s_waitcnt vmcnt(0)" ::: "memory");       // stage(31) landed
  __builtin_amdgcn_s_barrier();
  __builtin_amdgcn_s_setprio(1);
  mfma16(afA, bh, 4);
  readA(1, afB);                        // af(31)
  __builtin_amdgcn_s_setprio(0);
  __builtin_amdgcn_s_barrier();
  readB(1, 0, bl);
  readB(1, 1, bh);
  __builtin_amdgcn_s_barrier();
  __builtin_amdgcn_s_setprio(1);
  mfma16(afB, bl, 0);
  mfma16(afB, bh, 4);
  __builtin_amdgcn_s_setprio(0);

  // ---- epilogue: tanh + dot(w_v), wave reduce, LDS cross-wave reduce ----
  float p[4][4];
  #pragma unroll
  for (int mi = 0; mi < 4; ++mi)
    #pragma unroll
    for (int r = 0; r < 4; ++r) p[mi][r] = 0.f;

  #pragma unroll
  for (int ni = 0; ni < 8; ++ni) {
    const int n = wn * 128 + ni * 16 + col16;
    const float hb = hproj[b * HD + n] + b_attn[n];
    const float wv = w_v[n];
    #pragma unroll
    for (int mi = 0; mi < 4; ++mi) {
      #pragma unroll
      for (int r = 0; r < 4; ++r) {
        float x = fminf(fmaxf(acc[mi][ni][r] + hb, -15.f), 15.f);
        float ex = __expf(2.f * x);
        p[mi][r] += wv * __fdividef(ex - 1.f, ex + 1.f);
      }
    }
  }
  #pragma unroll
  for (int off = 8; off >= 1; off >>= 1) {
    #pragma unroll
    for (int mi = 0; mi < 4; ++mi)
      #pragma unroll
      for (int r = 0; r < 4; ++r)
        p[mi][r] += __shfl_xor(p[mi][r], off, 64);
  }

  float* red = (float*)&As[0][0];      // 512 floats, reuses dead A buffer
  __syncthreads();
  if (col16 == 0) {
    #pragma unroll
    for (int mi = 0; mi < 4; ++mi)
      #pragma unroll
      for (int r = 0; r < 4; ++r)
        red[wn * 128 + wm * 64 + mi * 16 + q * 4 + r] = p[mi][r];
  }
  __syncthreads();
  if (tid < 128) {
    const float v = red[tid] + red[128 + tid] + red[256 + tid] + red[384 + tid];
    scores[b * SEQ + s0 + tid] = v;
  }
}

// ---------- kernel 3: softmax over S, in place ----------
__global__ void softmax_kernel(float* __restrict__ scores) {
  const int b = blockIdx.x;
  float* sc = scores + b * SEQ;
  __shared__ float red[16];
  const int tid = threadIdx.x;   // 256
  float loc[16];
  float mx = -1e30f;
  #pragma unroll
  for (int i = 0; i < 16; ++i) { loc[i] = sc[i * 256 + tid]; mx = fmaxf(mx, loc[i]); }
  #pragma unroll
  for (int off = 32; off >= 1; off >>= 1) mx = fmaxf(mx, __shfl_xor(mx, off, 64));
  if ((tid & 63) == 0) red[tid >> 6] = mx;
  __syncthreads();
  mx = fmaxf(fmaxf(red[0], red[1]), fmaxf(red[2], red[3]));
  float sum = 0.f;
  #pragma unroll
  for (int i = 0; i < 16; ++i) { loc[i] = __expf(loc[i] - mx); sum += loc[i]; }
  #pragma unroll
  for (int off = 32; off >= 1; off >>= 1) sum += __shfl_xor(sum, off, 64);
  if ((tid & 63) == 0) red[8 + (tid >> 6)] = sum;
  __syncthreads();
  sum = red[8] + red[9] + red[10] + red[11];
  const float inv = 1.0f / sum;
  #pragma unroll
  for (int i = 0; i < 16; ++i) sc[i * 256 + tid] = loc[i] * inv;
}

// ---------- kernel 4: context[b,d] = sum_s attn[b,s] * enc[b,s,d] ----------
__global__ __launch_bounds__(256) void context_kernel(const float* __restrict__ attn,
                                                      const float* __restrict__ enc,
                                                      float* __restrict__ out) {
  const int b  = blockIdx.y;
  const int s0 = blockIdx.x * 64;
  const int tid = threadIdx.x;   // 256 threads * float4 = 1024 d
  const float* encB = enc + ((size_t)b * SEQ + s0) * D2 + tid * 4;
  const float* at   = attn + b * SEQ + s0;
  f32x4 acc0 = {0.f, 0.f, 0.f, 0.f}, acc1 = {0.f, 0.f, 0.f, 0.f};
  #pragma unroll 8
  for (int i = 0; i < 64; i += 2) {
    acc0 += at[i]     * *(const f32x4*)(encB + (size_t)i * D2);
    acc1 += at[i + 1] * *(const f32x4*)(encB + (size_t)(i + 1) * D2);
  }
  f32x4 acc = acc0 + acc1;
  float* o = out + b * D2 + tid * 4;
  atomicAdd(o + 0, acc[0]);
  atomicAdd(o + 1, acc[1]);
  atomicAdd(o + 2, acc[2]);
  atomicAdd(o + 3, acc[3]);
}

extern "C" void kernel_launch(void* const* d_in, const int* in_sizes, int n_in,
                              void* d_out, int out_size, void* d_ws, size_t ws_size,
                              hipStream_t stream) {
  (void)in_sizes; (void)n_in; (void)ws_size;
  const float* hidden = (const float*)d_in[0];   // [16,1024]
  const float* enc    = (const float*)d_in[1];   // [16,4096,1024]
  const float* W      = (const float*)d_in[2];   // [2048,512]
  const float* b_attn = (const float*)d_in[3];   // [512]
  const float* w_v    = (const float*)d_in[4];   // [512]
  float* out = (float*)d_out;                    // [16,1024]

  char* ws = (char*)d_ws;
  _Float16* WtS = (_Float16*)ws;                     // 1 MB shuffled Wbot f16
  float* hproj  = (float*)(ws + (1 << 20));          // 32 KB
  float* scores = (float*)(ws + (1 << 20) + 32768);  // 256 KB (reused as attn)

  hipMemsetAsync(d_out, 0, (size_t)out_size * sizeof(float), stream);
  hipMemsetAsync(hproj, 0, BAT * HD * sizeof(float), stream);

  wconv_kernel  <<<dim3(32, 32),          256, 0, stream>>>(W, WtS);
  hproj_kernel  <<<dim3(128),             256, 0, stream>>>(hidden, W, hproj);
  scores_kernel <<<dim3(SEQ / BM, BAT),   512, 0, stream>>>(enc, WtS, hproj, b_attn, w_v, scores);
  softmax_kernel<<<dim3(BAT),             256, 0, stream>>>(scores);
  context_kernel<<<dim3(SEQ / 64, BAT),   256, 0, stream>>>(scores, enc, out);
}

// Round 5
// 469.973 us; speedup vs baseline: 1.0408x; 1.0075x over previous
//
#include <hip/hip_runtime.h>
#include <hip/hip_bf16.h>
#include <math.h>

#define HD   512
#define D2   1024
#define SEQ  4096
#define BAT  16
#define BM   128     // s-rows per block
#define BK   32      // k per step
#define NKT  32      // 1024 / BK

typedef _Float16 half8 __attribute__((ext_vector_type(8)));
typedef float    f32x4 __attribute__((ext_vector_type(4)));
typedef __attribute__((address_space(3))) void lds_void_t;
typedef __attribute__((address_space(1))) void glb_void_t;

// ---------- kernel 0: W bottom-half -> f16, shuffled tile-major ----------
// WtS chunk layout: [kt 0..31][c 0..2047] of 16B chunks,
// c = (nh*16+nbl)*64 + kc*16 + nlo ; n = nh*256 + nbl*16 + nlo ; k = kt*32 + kc*8 + j.
// This is exactly MFMA B-fragment order: a wave's 8 frag loads are 8x 1KB
// contiguous coalesced reads -> B can live in registers straight from L2.
__global__ void wconv_kernel(const float* __restrict__ W, _Float16* __restrict__ WtS) {
  __shared__ float tile[32][17];
  const int kt  = blockIdx.x;        // 0..31
  const int nbg = blockIdx.y;        // 0..31
  const int nh  = nbg >> 4, nbl = nbg & 15;
  const int t   = threadIdx.x;       // 256
  {
    const int n16 = t & 15, kk = t >> 4;   // kk 0..15
    #pragma unroll
    for (int i = 0; i < 2; ++i) {
      const int k = kk + i * 16;
      tile[k][n16] = W[(size_t)(D2 + kt * 32 + k) * HD + nh * 256 + nbl * 16 + n16];
    }
  }
  __syncthreads();
  if (t < 64) {
    const int kc = t >> 4, nlo = t & 15;
    half8 h;
    #pragma unroll
    for (int j = 0; j < 8; ++j) h[j] = (_Float16)tile[kc * 8 + j][nlo];
    *(half8*)(WtS + ((size_t)(kt * 2 + nh) * 1024 + nbl * 64 + kc * 16 + nlo) * 8) = h;
  }
}

// ---------- kernel 1: h_proj[b,h] = hidden[b,:] . W_top[:,h] (atomic) ----------
__global__ void hproj_kernel(const float* __restrict__ hidden,
                             const float* __restrict__ W,
                             float* __restrict__ hproj) {
  const int b  = blockIdx.x >> 3;
  const int kc = blockIdx.x & 7;
  const int h  = threadIdx.x;
  float a0 = 0.f, a1 = 0.f;
  #pragma unroll 4
  for (int i = 0; i < 128; ++i) {
    const int d = kc * 128 + i;
    const float hd = hidden[b * D2 + d];
    a0 += hd * W[(size_t)d * HD + h];
    a1 += hd * W[(size_t)d * HD + h + 256];
  }
  atomicAdd(&hproj[b * HD + h], a0);
  atomicAdd(&hproj[b * HD + h + 256], a1);
}

// ---------- kernel 2: scores = w_v . tanh(enc.Wbot + h_proj + b_attn) ----------
// 128x512 tile, 512 thr (8 waves, wave tile 64x128), BK=32.
// B: global->REGISTER double-buffer from L2 (WtS is frag-ordered, 1 MB).
// A: LDS-only, 4 buffers x 16 KB, 3-deep global_load_lds prefetch.
// ONE barrier per K-step; counted vmcnt keeps {A+2, B+1, A+3} = 12 loads
// in flight at every wait (A-stream never drained in the main loop).
__global__ __launch_bounds__(512, 2) void scores_kernel(
    const float* __restrict__ enc, const _Float16* __restrict__ WtS,
    const float* __restrict__ hproj, const float* __restrict__ b_attn,
    const float* __restrict__ w_v, float* __restrict__ scores)
{
  __shared__ __align__(16) float As[4][BM * BK];   // 16 KB x4, f32, xor-swizzled chunks

  const int s0  = blockIdx.x * BM;
  const int b   = blockIdx.y;
  const int kt0 = (blockIdx.x + blockIdx.y) & 31;  // per-block K-phase rotation (R4: +8%)
  const int tid = threadIdx.x, lane = tid & 63, w = tid >> 6;
  const int col16 = lane & 15, q = lane >> 4;
  const int wm = w >> 2, wn = w & 3;   // wave tile: rows [wm*64,+64), cols [wn*128,+128)

  const float* encB = enc + ((size_t)b * SEQ + s0) * D2;

  f32x4 acc[4][8];
  const f32x4 z = {0.f, 0.f, 0.f, 0.f};
  #pragma unroll
  for (int mi = 0; mi < 4; ++mi)
    #pragma unroll
    for (int ni = 0; ni < 8; ++ni) acc[mi][ni] = z;

  auto stageA = [&](int ktp, int buf) {
    // LDS slot s <- enc[row = s>>3][ktp*32 + ((s&7)^(row&7))*4 ..+4)  (16B each)
    const float* ek = encB + ktp * BK;
    #pragma unroll
    for (int i = 0; i < 2; ++i) {
      const int s = i * 512 + tid;
      const int row = s >> 3;
      const int g = (s & 7) ^ (row & 7);
      __builtin_amdgcn_global_load_lds((glb_void_t*)(ek + (size_t)row * D2 + g * 4),
          (lds_void_t*)((char*)&As[0][0] + (size_t)buf * 16384 + s * 16), 16, 0, 0);
    }
  };
  auto loadB = [&](int ktp, half8* bf) {
    const _Float16* wk = WtS + (size_t)ktp * 16384;
    #pragma unroll
    for (int ni = 0; ni < 8; ++ni)
      bf[ni] = *(const half8*)(wk + ((size_t)((wn * 8 + ni) * 64 + q * 16 + col16)) * 8);
  };
  auto compute = [&](int buf, const half8* bf) {
    const float* pA = &As[0][0] + (size_t)buf * 4096;
    half8 af[4];
    #pragma unroll
    for (int mi = 0; mi < 4; ++mi) {
      const int row = wm * 64 + mi * 16 + col16;
      const int rb = row * 8, rx = row & 7;
      const f32x4 lo = *(const f32x4*)&pA[(rb + ((2 * q)     ^ rx)) * 4];
      const f32x4 hi = *(const f32x4*)&pA[(rb + ((2 * q + 1) ^ rx)) * 4];
      half8 h;
      h[0] = (_Float16)lo[0]; h[1] = (_Float16)lo[1];
      h[2] = (_Float16)lo[2]; h[3] = (_Float16)lo[3];
      h[4] = (_Float16)hi[0]; h[5] = (_Float16)hi[1];
      h[6] = (_Float16)hi[2]; h[7] = (_Float16)hi[3];
      af[mi] = h;
    }
    __builtin_amdgcn_s_setprio(1);
    #pragma unroll
    for (int ni = 0; ni < 8; ++ni)
      #pragma unroll
      for (int mi = 0; mi < 4; ++mi)
        acc[mi][ni] = __builtin_amdgcn_mfma_f32_16x16x32_f16(af[mi], bf[ni], acc[mi][ni], 0, 0, 0);
    __builtin_amdgcn_s_setprio(0);
  };

  half8 BE[8], BO[8];   // B register double-buffer (parity-named, rule #20)

  // ---- prologue: A0..A2 staged, B0 in regs ----
  stageA(kt0, 0);
  stageA((kt0 + 1) & 31, 1);
  stageA((kt0 + 2) & 31, 2);
  loadB(kt0, BE);

  // ---- main loop kt = 0..27, paired for B-reg parity ----
  // per iter: loadB(kt+1) | barrier | stageA(kt+3) | vmcnt(12) | compute(kt)
  // in-flight after wait: {A(kt+2), B(kt+1), A(kt+3)} = 12 (A never drained)
  for (int kt = 0; kt < 28; kt += 2) {
    loadB((kt + 1 + kt0) & 31, BO);
    __builtin_amdgcn_s_barrier();
    stageA((kt + 3 + kt0) & 31, (kt + 3) & 3);
    asm volatile("s_waitcnt vmcnt(12)" ::: "memory");
    compute(kt & 3, BE);

    loadB((kt + 2 + kt0) & 31, BE);
    __builtin_amdgcn_s_barrier();
    stageA((kt + 4 + kt0) & 31, (kt + 4) & 3);
    asm volatile("s_waitcnt vmcnt(12)" ::: "memory");
    compute((kt + 1) & 3, BO);
  }

  // ---- tail kt = 28..31 (waits: 12, 10, 8, 0) ----
  loadB((29 + kt0) & 31, BO);
  __builtin_amdgcn_s_barrier();
  stageA((31 + kt0) & 31, 3);
  asm volatile("s_waitcnt vmcnt(12)" ::: "memory");
  compute(0, BE);                       // kt=28

  loadB((30 + kt0) & 31, BE);
  __builtin_amdgcn_s_barrier();
  asm volatile("s_waitcnt vmcnt(10)" ::: "memory");
  compute(1, BO);                       // kt=29

  loadB((31 + kt0) & 31, BO);
  __builtin_amdgcn_s_barrier();
  asm volatile("s_waitcnt vmcnt(8)" ::: "memory");
  compute(2, BE);                       // kt=30

  __builtin_amdgcn_s_barrier();
  asm volatile("s_waitcnt vmcnt(0)" ::: "memory");
  compute(3, BO);                       // kt=31

  // ---- epilogue: tanh + dot(w_v), wave reduce, LDS cross-wave reduce ----
  float p[4][4];
  #pragma unroll
  for (int mi = 0; mi < 4; ++mi)
    #pragma unroll
    for (int r = 0; r < 4; ++r) p[mi][r] = 0.f;

  #pragma unroll
  for (int ni = 0; ni < 8; ++ni) {
    const int n = wn * 128 + ni * 16 + col16;
    const float hb = hproj[b * HD + n] + b_attn[n];
    const float wv = w_v[n];
    #pragma unroll
    for (int mi = 0; mi < 4; ++mi) {
      #pragma unroll
      for (int r = 0; r < 4; ++r) {
        float x = fminf(fmaxf(acc[mi][ni][r] + hb, -15.f), 15.f);
        float ex = __expf(2.f * x);
        p[mi][r] += wv * __fdividef(ex - 1.f, ex + 1.f);
      }
    }
  }
  #pragma unroll
  for (int off = 8; off >= 1; off >>= 1) {
    #pragma unroll
    for (int mi = 0; mi < 4; ++mi)
      #pragma unroll
      for (int r = 0; r < 4; ++r)
        p[mi][r] += __shfl_xor(p[mi][r], off, 64);
  }

  float* red = (float*)&As[0][0];      // 512 floats, reuses dead A buffer
  __syncthreads();
  if (col16 == 0) {
    #pragma unroll
    for (int mi = 0; mi < 4; ++mi)
      #pragma unroll
      for (int r = 0; r < 4; ++r)
        red[wn * 128 + wm * 64 + mi * 16 + q * 4 + r] = p[mi][r];
  }
  __syncthreads();
  if (tid < 128) {
    const float v = red[tid] + red[128 + tid] + red[256 + tid] + red[384 + tid];
    scores[b * SEQ + s0 + tid] = v;
  }
}

// ---------- kernel 3: softmax over S, in place ----------
__global__ void softmax_kernel(float* __restrict__ scores) {
  const int b = blockIdx.x;
  float* sc = scores + b * SEQ;
  __shared__ float red[16];
  const int tid = threadIdx.x;   // 256
  float loc[16];
  float mx = -1e30f;
  #pragma unroll
  for (int i = 0; i < 16; ++i) { loc[i] = sc[i * 256 + tid]; mx = fmaxf(mx, loc[i]); }
  #pragma unroll
  for (int off = 32; off >= 1; off >>= 1) mx = fmaxf(mx, __shfl_xor(mx, off, 64));
  if ((tid & 63) == 0) red[tid >> 6] = mx;
  __syncthreads();
  mx = fmaxf(fmaxf(red[0], red[1]), fmaxf(red[2], red[3]));
  float sum = 0.f;
  #pragma unroll
  for (int i = 0; i < 16; ++i) { loc[i] = __expf(loc[i] - mx); sum += loc[i]; }
  #pragma unroll
  for (int off = 32; off >= 1; off >>= 1) sum += __shfl_xor(sum, off, 64);
  if ((tid & 63) == 0) red[8 + (tid >> 6)] = sum;
  __syncthreads();
  sum = red[8] + red[9] + red[10] + red[11];
  const float inv = 1.0f / sum;
  #pragma unroll
  for (int i = 0; i < 16; ++i) sc[i * 256 + tid] = loc[i] * inv;
}

// ---------- kernel 4: context[b,d] = sum_s attn[b,s] * enc[b,s,d] ----------
__global__ __launch_bounds__(256) void context_kernel(const float* __restrict__ attn,
                                                      const float* __restrict__ enc,
                                                      float* __restrict__ out) {
  const int b  = blockIdx.y;
  const int s0 = blockIdx.x * 64;
  const int tid = threadIdx.x;   // 256 threads * float4 = 1024 d
  const float* encB = enc + ((size_t)b * SEQ + s0) * D2 + tid * 4;
  const float* at   = attn + b * SEQ + s0;
  f32x4 acc0 = {0.f, 0.f, 0.f, 0.f}, acc1 = {0.f, 0.f, 0.f, 0.f};
  #pragma unroll 8
  for (int i = 0; i < 64; i += 2) {
    acc0 += at[i]     * *(const f32x4*)(encB + (size_t)i * D2);
    acc1 += at[i + 1] * *(const f32x4*)(encB + (size_t)(i + 1) * D2);
  }
  f32x4 acc = acc0 + acc1;
  float* o = out + b * D2 + tid * 4;
  atomicAdd(o + 0, acc[0]);
  atomicAdd(o + 1, acc[1]);
  atomicAdd(o + 2, acc[2]);
  atomicAdd(o + 3, acc[3]);
}

extern "C" void kernel_launch(void* const* d_in, const int* in_sizes, int n_in,
                              void* d_out, int out_size, void* d_ws, size_t ws_size,
                              hipStream_t stream) {
  (void)in_sizes; (void)n_in; (void)ws_size;
  const float* hidden = (const float*)d_in[0];   // [16,1024]
  const float* enc    = (const float*)d_in[1];   // [16,4096,1024]
  const float* W      = (const float*)d_in[2];   // [2048,512]
  const float* b_attn = (const float*)d_in[3];   // [512]
  const float* w_v    = (const float*)d_in[4];   // [512]
  float* out = (float*)d_out;                    // [16,1024]

  char* ws = (char*)d_ws;
  _Float16* WtS = (_Float16*)ws;                     // 1 MB shuffled Wbot f16
  float* hproj  = (float*)(ws + (1 << 20));          // 32 KB
  float* scores = (float*)(ws + (1 << 20) + 32768);  // 256 KB (reused as attn)

  hipMemsetAsync(d_out, 0, (size_t)out_size * sizeof(float), stream);
  hipMemsetAsync(hproj, 0, BAT * HD * sizeof(float), stream);

  wconv_kernel  <<<dim3(32, 32),          256, 0, stream>>>(W, WtS);
  hproj_kernel  <<<dim3(128),             256, 0, stream>>>(hidden, W, hproj);
  scores_kernel <<<dim3(SEQ / BM, BAT),   512, 0, stream>>>(enc, WtS, hproj, b_attn, w_v, scores);
  softmax_kernel<<<dim3(BAT),             256, 0, stream>>>(scores);
  context_kernel<<<dim3(SEQ / 64, BAT),   256, 0, stream>>>(scores, enc, out);
}